// Round 11
// baseline (201.885 us; speedup 1.0000x reference)
//
#include <hip/hip_runtime.h>
#include <hip/hip_bf16.h>

typedef short bf16x8 __attribute__((ext_vector_type(8)));
typedef _Float16 f16;
typedef f16 f16x8 __attribute__((ext_vector_type(8)));
typedef float f32x4 __attribute__((ext_vector_type(4)));
typedef unsigned short u16;
typedef u16 u16x8 __attribute__((ext_vector_type(8)));
typedef unsigned int u32;
typedef u32 u32x2 __attribute__((ext_vector_type(2)));

#define B_  2
#define L_  4096
#define F_  512
#define H_  8
#define D_  64
#define M_  8192       // B_*L_
#define NSPL 2         // flash split-K factor
#define KHALF (L_ / NSPL)

#define LOG2E 1.442695041f

__device__ inline u16 f2bf(float f) {
    union { float f; unsigned u; } v; v.f = f;
    unsigned r = v.u + 0x7fff + ((v.u >> 16) & 1);  // RNE
    return (u16)(r >> 16);
}
__device__ inline u16 f2h(float f) {
    union { f16 h; u16 u; } v; v.h = (f16)f;  // RNE hw cvt
    return v.u;
}
__device__ inline float h2f(u16 u) {
    union { u16 u; f16 h; } v; v.u = u;
    return (float)v.h;
}

// ---------------------------------------------------------------------------
// Fused weight transpose: W [512 k][512 n] fp32 -> Wt [512 n][512 k] fp16.
// ---------------------------------------------------------------------------
__global__ __launch_bounds__(256) void wt_kernel(
    const float* __restrict__ Wq, const float* __restrict__ Wk,
    const float* __restrict__ Wv, const float* __restrict__ Wo,
    u16* __restrict__ Tq, u16* __restrict__ Tk,
    u16* __restrict__ Tv, u16* __restrict__ To) {
    __shared__ float t[32][33];
    const int z = blockIdx.z;
    const float* in = (z == 0) ? Wq : (z == 1) ? Wk : (z == 2) ? Wv : Wo;
    u16* out = (z == 0) ? Tq : (z == 1) ? Tk : (z == 2) ? Tv : To;
    int k0 = blockIdx.y * 32, n0 = blockIdx.x * 32;
    int c = threadIdx.x & 31, r8 = threadIdx.x >> 5;
#pragma unroll
    for (int i = 0; i < 4; ++i) {
        int r = r8 * 4 + i;
        t[r][c] = in[(size_t)(k0 + r) * F_ + n0 + c];
    }
    __syncthreads();
#pragma unroll
    for (int i = 0; i < 4; ++i) {
        int r = r8 * 4 + i;
        out[(size_t)(n0 + r) * F_ + k0 + c] = f2h(t[c][r]);
    }
}

// ---------------------------------------------------------------------------
// Fused projection kernel (R9 form, reverted from R10's z-uniform split:
// the uniform split re-read+re-converted Xkv and cost ~3 µs net).
// 128x64 tile, m-major grid (XCD = m%8 owns a 2+2 MB A panel, L2-local).
// z=0: Q = Xq*Wq (scaled log2e) -> [B,H,L,D] fp16.
// z=1: K -> [B,H,L,D] fp16;  V -> [B,H,D,L] bf16 transposed (A read once).
// ---------------------------------------------------------------------------
__global__ __launch_bounds__(256, 3) void proj_kernel(
    const float* __restrict__ Xq, const float* __restrict__ Xkv,
    const u16* __restrict__ Wqt, const u16* __restrict__ Wkt,
    const u16* __restrict__ Wvt,
    u16* __restrict__ Qw, u16* __restrict__ Kw, u16* __restrict__ Vw) {
    __shared__ u16 Ah[128][72];
    __shared__ u16 B1[64][72];
    __shared__ u16 B2[64][72];
    const int tid = threadIdx.x;
    const int w = tid >> 6, lane = tid & 63, lx = lane & 15, quad = lane >> 4;
    const int m0 = blockIdx.x * 128, n0 = blockIdx.y * 64;
    const bool isKV = (blockIdx.z == 1);
    const float* A = isKV ? Xkv : Xq;
    const u16* W1 = isKV ? Wkt : Wqt;

    float4 apre[8];
    u16x8 b1p[2], b2p[2];

    auto load_ab = [&](int k0) {
#pragma unroll
        for (int it = 0; it < 4; ++it) {
            int slot = tid + it * 256, r = slot >> 3, g = (slot & 7) * 8;
            apre[2 * it]     = *(const float4*)(A + (size_t)(m0 + r) * F_ + k0 + g);
            apre[2 * it + 1] = *(const float4*)(A + (size_t)(m0 + r) * F_ + k0 + g + 4);
        }
#pragma unroll
        for (int it = 0; it < 2; ++it) {
            int slot = tid + it * 256, r = slot >> 3, g = (slot & 7) * 8;
            b1p[it] = *(const u16x8*)(W1 + (size_t)(n0 + r) * F_ + k0 + g);
            if (isKV)
                b2p[it] = *(const u16x8*)(Wvt + (size_t)(n0 + r) * F_ + k0 + g);
        }
    };
    auto write_ab = [&]() {
#pragma unroll
        for (int it = 0; it < 4; ++it) {
            int slot = tid + it * 256, r = slot >> 3, g = (slot & 7) * 8;
            float4 f0 = apre[2 * it], f1 = apre[2 * it + 1];
            u16 th[8] = {f2h(f0.x), f2h(f0.y), f2h(f0.z), f2h(f0.w),
                         f2h(f1.x), f2h(f1.y), f2h(f1.z), f2h(f1.w)};
            *(u16x8*)&Ah[r][g] = *(u16x8*)th;
        }
#pragma unroll
        for (int it = 0; it < 2; ++it) {
            int slot = tid + it * 256, r = slot >> 3, g = (slot & 7) * 8;
            *(u16x8*)&B1[r][g] = b1p[it];
            if (isKV) *(u16x8*)&B2[r][g] = b2p[it];
        }
    };

    f32x4 acc1[2][4] = {}, acc2[2][4] = {};

    load_ab(0);
    write_ab();
    __syncthreads();
    load_ab(64);   // in flight during first compute

    for (int k0 = 0; k0 < F_; k0 += 64) {
#pragma unroll
        for (int ks = 0; ks < 2; ++ks) {
            f16x8 af[2];
#pragma unroll
            for (int mf = 0; mf < 2; ++mf)
                af[mf] = *(const f16x8*)&Ah[w * 32 + mf * 16 + lx][ks * 32 + quad * 8];
#pragma unroll
            for (int nt = 0; nt < 4; ++nt) {
                f16x8 b1 = *(const f16x8*)&B1[nt * 16 + lx][ks * 32 + quad * 8];
#pragma unroll
                for (int mf = 0; mf < 2; ++mf)
                    acc1[mf][nt] = __builtin_amdgcn_mfma_f32_16x16x32_f16(af[mf], b1, acc1[mf][nt], 0, 0, 0);
                if (isKV) {
                    f16x8 b2 = *(const f16x8*)&B2[nt * 16 + lx][ks * 32 + quad * 8];
#pragma unroll
                    for (int mf = 0; mf < 2; ++mf)
                        acc2[mf][nt] = __builtin_amdgcn_mfma_f32_16x16x32_f16(af[mf], b2, acc2[mf][nt], 0, 0, 0);
                }
            }
        }
        if (k0 < F_ - 64) {
            __syncthreads();   // loads for k0+64 landed during this compute
            write_ab();
            __syncthreads();
            if (k0 < F_ - 128) load_ab(k0 + 128);  // issued AFTER barriers
        }
    }

    const int h = n0 >> 6;
    const float scl = isKV ? 1.0f : LOG2E;
    u16* C1 = isKV ? Kw : Qw;
#pragma unroll
    for (int mf = 0; mf < 2; ++mf)
#pragma unroll
        for (int nt = 0; nt < 4; ++nt)
#pragma unroll
            for (int i = 0; i < 4; ++i) {
                int m = m0 + w * 32 + mf * 16 + quad * 4 + i;
                int b = m >> 12, l = m & 4095;
                int d = nt * 16 + lx;
                C1[((size_t)(b * H_ + h) * L_ + l) * D_ + d] = f2h(acc1[mf][nt][i] * scl);
            }
    if (isKV) {
        __syncthreads();
#pragma unroll
        for (int mf = 0; mf < 2; ++mf)
#pragma unroll
            for (int nt = 0; nt < 4; ++nt)
#pragma unroll
                for (int i = 0; i < 4; ++i)
                    Ah[w * 32 + mf * 16 + quad * 4 + i][nt * 16 + lx] = f2bf(acc2[mf][nt][i]);
        __syncthreads();
        int d = tid >> 2, seg = (tid & 3) * 32;
        int b = m0 >> 12;
        u16 tmp[32];
#pragma unroll
        for (int j = 0; j < 32; ++j) tmp[j] = Ah[seg + j][d];
        size_t base = ((size_t)(b * H_ + h) * D_ + d) * L_ + (m0 & 4095) + seg;
#pragma unroll
        for (int c = 0; c < 4; ++c)
            *(u16x8*)(Vw + base + c * 8) = *(u16x8*)&tmp[c * 8];
    }
}

// ---------------------------------------------------------------------------
// Out-projection GEMM, 128x128 tile, m-major grid (XCD = m%8, L2-local).
// ---------------------------------------------------------------------------
__global__ __launch_bounds__(256) void out_gemm(const u16* __restrict__ A16,
                                                const u16* __restrict__ Wt,
                                                float* __restrict__ Cf) {
    __shared__ u16 As[128][72];
    __shared__ u16 Bs[128][72];
    const int tid = threadIdx.x;
    const int w = tid >> 6, lane = tid & 63, lx = lane & 15, quad = lane >> 4;
    const int m0 = blockIdx.x * 128, n0 = blockIdx.y * 128;

    u16x8 a16p[4];
    u16x8 bp[4];

    auto load_ab = [&](int k0) {
#pragma unroll
        for (int it = 0; it < 4; ++it) {
            int slot = tid + it * 256, r = slot >> 3, g = (slot & 7) * 8;
            a16p[it] = *(const u16x8*)(A16 + (size_t)(m0 + r) * F_ + k0 + g);
            bp[it]   = *(const u16x8*)(Wt  + (size_t)(n0 + r) * F_ + k0 + g);
        }
    };
    auto write_ab = [&]() {
#pragma unroll
        for (int it = 0; it < 4; ++it) {
            int slot = tid + it * 256, r = slot >> 3, g = (slot & 7) * 8;
            *(u16x8*)&As[r][g] = a16p[it];
            *(u16x8*)&Bs[r][g] = bp[it];
        }
    };

    f32x4 acc[2][8] = {};

    load_ab(0);
    write_ab();
    __syncthreads();
    load_ab(64);

    for (int k0 = 0; k0 < F_; k0 += 64) {
#pragma unroll
        for (int ks = 0; ks < 2; ++ks) {
            f16x8 af[2];
#pragma unroll
            for (int mf = 0; mf < 2; ++mf)
                af[mf] = *(const f16x8*)&As[w * 32 + mf * 16 + lx][ks * 32 + quad * 8];
#pragma unroll
            for (int nt = 0; nt < 8; ++nt) {
                f16x8 bf = *(const f16x8*)&Bs[nt * 16 + lx][ks * 32 + quad * 8];
#pragma unroll
                for (int mf = 0; mf < 2; ++mf)
                    acc[mf][nt] = __builtin_amdgcn_mfma_f32_16x16x32_f16(af[mf], bf, acc[mf][nt], 0, 0, 0);
            }
        }
        if (k0 < F_ - 64) {
            __syncthreads();
            write_ab();
            __syncthreads();
            if (k0 < F_ - 128) load_ab(k0 + 128);
        }
    }

#pragma unroll
    for (int mf = 0; mf < 2; ++mf)
#pragma unroll
        for (int nt = 0; nt < 8; ++nt)
#pragma unroll
            for (int i = 0; i < 4; ++i) {
                int m = m0 + w * 32 + mf * 16 + quad * 4 + i;
                int n = n0 + nt * 16 + lx;
                Cf[(size_t)m * F_ + n] = acc[mf][nt][i];
            }
}

// ---------------------------------------------------------------------------
// MFMA flash attention, R11: R10 interleaved structure, setprio REMOVED
// (A/B test). Mechanism question: our SIMDs host 2 waves from different
// blocks (independent phases -> m191 says setprio helps) but each block is
// internally barrier-locked (m190 says it hurts). flash dur reads the
// verdict directly: rises => setprio was helping (restore next round);
// drops => it was hurting; +-1 us => null.
// At 77.1 us flash runs ~892 TF — at the guide's plain-HIP 8-warp attn
// reference. Further gains need the full HK 4-cluster combo (T16).
// ---------------------------------------------------------------------------
__global__ __launch_bounds__(256, 2) void flash_mfma(
    const u16* __restrict__ Qg, const u16* __restrict__ Kg,
    const u16* __restrict__ Vtg, u16* __restrict__ On, float* __restrict__ Ls) {
    __shared__ u16 Ks[2][64][72];   // fp16, double-buffered
    __shared__ u16 Vs[2][64][72];   // bf16, V^T tile [d][kcol], double-buffered

    const int tid = threadIdx.x;
    const int w = tid >> 6, lane = tid & 63, lx = lane & 15, quad = lane >> 4;

    // decode: 512 = 8 xcd * (2 head * 2 split * 16 qtile)
    const int x = blockIdx.x;
    const int t = x >> 3;
    const int hh = t >> 5;
    const int s = (t >> 4) & 1;
    const int bh = (x & 7) * 2 + hh;
    const int q0 = (t & 15) * 256;

    const u16* Qp = Qg + ((size_t)bh * L_ + q0) * D_;
    const u16* Kp = Kg + (size_t)bh * L_ * D_ + (size_t)(s * KHALF) * D_;
    const u16* Vp = Vtg + (size_t)bh * D_ * L_ + s * KHALF;

    // Q fragments straight to registers (B-operand layout), 64 q-rows/wave
    f16x8 qreg[4][2];
#pragma unroll
    for (int qf = 0; qf < 4; ++qf)
#pragma unroll
        for (int ks = 0; ks < 2; ++ks)
            qreg[qf][ks] = *(const f16x8*)(Qp + (size_t)(w * 64 + qf * 16 + lx) * D_ +
                                           ks * 32 + quad * 8);

    u16x8 kp[2], vp[2];
    auto load_kv = [&](int kt) {
#pragma unroll
        for (int it = 0; it < 2; ++it) {
            int slot = tid + it * 256, r = slot >> 3, g = (slot & 7) * 8;
            kp[it] = *(const u16x8*)(Kp + (size_t)(kt * 64 + r) * D_ + g);
            vp[it] = *(const u16x8*)(Vp + (size_t)r * L_ + kt * 64 + g);
        }
    };
    auto write_kv = [&](int p) {
#pragma unroll
        for (int it = 0; it < 2; ++it) {
            int slot = tid + it * 256, r = slot >> 3, g = (slot & 7) * 8;
            *(u16x8*)&Ks[p][r][g] = kp[it];
            *(u16x8*)&Vs[p][r][g] = vp[it];
        }
    };

    // softmax of one half for one qf: sv pair -> bf16 A-fragment (permlane)
    auto smqf = [&](const f32x4& s0, const f32x4& s1) -> bf16x8 {
        u32 ub0[4], ub1[4];
#pragma unroll
        for (int i = 0; i < 4; ++i) {
            ub0[i] = __float_as_uint(__builtin_amdgcn_exp2f(s0[i]));
            ub1[i] = __float_as_uint(__builtin_amdgcn_exp2f(s1[i]));
        }
        u32 pu0 = __builtin_amdgcn_perm(ub0[1], ub0[0], 0x07060302u);
        u32 pw0 = __builtin_amdgcn_perm(ub0[3], ub0[2], 0x07060302u);
        u32 pu1 = __builtin_amdgcn_perm(ub1[1], ub1[0], 0x07060302u);
        u32 pw1 = __builtin_amdgcn_perm(ub1[3], ub1[2], 0x07060302u);
        u32x2 r  = __builtin_amdgcn_permlane32_swap(pu0, pu1, false, false);
        u32x2 r2 = __builtin_amdgcn_permlane16_swap(r[0], r[1], false, false);
        u32x2 tt = __builtin_amdgcn_permlane32_swap(pw0, pw1, false, false);
        u32x2 t2 = __builtin_amdgcn_permlane16_swap(tt[0], tt[1], false, false);
        union { u32 d[4]; bf16x8 h; } cvt;
        cvt.d[0] = r2[0];
        cvt.d[1] = t2[0];
        cvt.d[2] = r2[1];
        cvt.d[3] = t2[1];
        return cvt.h;
    };

    const bf16x8 vone = {0x3F80, 0x3F80, 0x3F80, 0x3F80,
                         0x3F80, 0x3F80, 0x3F80, 0x3F80};  // bf16 1.0 x8
    f32x4 o[4][4] = {};
    f32x4 osum[4] = {};

    load_kv(0);
    write_kv(0);
    __syncthreads();
    load_kv(1);   // in flight during first compute

    const int NT = KHALF / 64;
    for (int kt = 0; kt < NT; ++kt) {
        const int p = kt & 1;

        // ---- section 1: QK half A (nt 0,1), 16 MFMAs ---------------------
        // S^T = K Q^T : lane holds S^T[k=nt*16+quad*4+i][q=w*64+qf*16+lx]
        f32x4 sv[4][4] = {};
#pragma unroll
        for (int ks = 0; ks < 2; ++ks)
#pragma unroll
            for (int nt = 0; nt < 2; ++nt) {
                f16x8 ak = *(const f16x8*)&Ks[p][nt * 16 + lx][ks * 32 + quad * 8];
#pragma unroll
                for (int qf = 0; qf < 4; ++qf)
                    sv[nt][qf] = __builtin_amdgcn_mfma_f32_16x16x32_f16(ak, qreg[qf][ks], sv[nt][qf], 0, 0, 0);
            }

        // hoist half-B K fragments (4 ds_reads) for the interleave
        f16x8 akB[2][2];  // [ks][nt-2]
#pragma unroll
        for (int ks = 0; ks < 2; ++ks)
#pragma unroll
            for (int nt = 0; nt < 2; ++nt)
                akB[ks][nt] = *(const f16x8*)&Ks[p][(nt + 2) * 16 + lx][ks * 32 + quad * 8];

        // ---- section 2: per qf {4 QK_B MFMAs ; SM_A(qf) VALU} ------------
        bf16x8 apA[4];
#pragma unroll
        for (int qf = 0; qf < 4; ++qf) {
            sv[2][qf] = __builtin_amdgcn_mfma_f32_16x16x32_f16(akB[0][0], qreg[qf][0], sv[2][qf], 0, 0, 0);
            sv[3][qf] = __builtin_amdgcn_mfma_f32_16x16x32_f16(akB[0][1], qreg[qf][0], sv[3][qf], 0, 0, 0);
            sv[2][qf] = __builtin_amdgcn_mfma_f32_16x16x32_f16(akB[1][0], qreg[qf][1], sv[2][qf], 0, 0, 0);
            sv[3][qf] = __builtin_amdgcn_mfma_f32_16x16x32_f16(akB[1][1], qreg[qf][1], sv[3][qf], 0, 0, 0);
            apA[qf] = smqf(sv[0][qf], sv[1][qf]);   // VALU fills MFMA shadow
        }

        // stage next tile into the other buffer (regs loaded ≥1 kt ago)
        if (kt < NT - 1) write_kv(p ^ 1);

        // hoist V fragments for half A (ds_reads)
        bf16x8 bvA[4];
#pragma unroll
        for (int nt = 0; nt < 4; ++nt)
            bvA[nt] = *(const bf16x8*)&Vs[p][nt * 16 + lx][quad * 8];

        // ---- section 3: per qf {5 PV_A MFMAs ; SM_B(qf) VALU} ------------
        bf16x8 apB[4];
#pragma unroll
        for (int qf = 0; qf < 4; ++qf) {
            osum[qf] = __builtin_amdgcn_mfma_f32_16x16x32_bf16(apA[qf], vone, osum[qf], 0, 0, 0);
#pragma unroll
            for (int nt = 0; nt < 4; ++nt)
                o[qf][nt] = __builtin_amdgcn_mfma_f32_16x16x32_bf16(apA[qf], bvA[nt], o[qf][nt], 0, 0, 0);
            apB[qf] = smqf(sv[2][qf], sv[3][qf]);   // VALU fills MFMA shadow
        }

        // ---- section 4: PV half B, 20 MFMAs ------------------------------
        bf16x8 bvB[4];
#pragma unroll
        for (int nt = 0; nt < 4; ++nt)
            bvB[nt] = *(const bf16x8*)&Vs[p][nt * 16 + lx][32 + quad * 8];
#pragma unroll
        for (int qf = 0; qf < 4; ++qf)
            osum[qf] = __builtin_amdgcn_mfma_f32_16x16x32_bf16(apB[qf], vone, osum[qf], 0, 0, 0);
#pragma unroll
        for (int nt = 0; nt < 4; ++nt) {
#pragma unroll
            for (int qf = 0; qf < 4; ++qf)
                o[qf][nt] = __builtin_amdgcn_mfma_f32_16x16x32_bf16(apB[qf], bvB[nt], o[qf][nt], 0, 0, 0);
        }

        if (kt < NT - 1) __syncthreads();  // drains LDS writes + OLD loads only
        if (kt < NT - 2) load_kv(kt + 2);  // issued AFTER the barrier
    }

    // write On = O/l (fp16, [B,L,H*D]) and l (f32)
    const int b = bh >> 3, h = bh & 7;
    u16* Op = On + (size_t)s * M_ * F_;
#pragma unroll
    for (int qf = 0; qf < 4; ++qf) {
        float linv[4];
#pragma unroll
        for (int i = 0; i < 4; ++i) linv[i] = 1.f / osum[qf][i];
#pragma unroll
        for (int nt = 0; nt < 4; ++nt)
#pragma unroll
            for (int i = 0; i < 4; ++i) {
                int l = q0 + w * 64 + qf * 16 + quad * 4 + i;
                Op[((size_t)b * L_ + l) * (H_ * D_) + h * D_ + nt * 16 + lx] =
                    f2h(o[qf][nt][i] * linv[i]);
            }
        if (lx == 0) {
            float* lp = Ls + ((size_t)s * (B_ * H_) + bh) * L_ +
                        q0 + w * 64 + qf * 16 + quad * 4;
#pragma unroll
            for (int i = 0; i < 4; ++i) lp[i] = osum[qf][i];
        }
    }
}

// ---------------------------------------------------------------------------
// Combine split-K partials: O = (l1*O1n + l2*O2n) / (l1+l2).
// ---------------------------------------------------------------------------
__global__ __launch_bounds__(256) void reduce_kernel(
    const u16* __restrict__ On, const float* __restrict__ Ls,
    u16* __restrict__ Ow) {
    int gid = blockIdx.x * 256 + threadIdx.x;  // u16x8 group, grid covers M_*F_/8
    size_t off = (size_t)gid * 8;
    int row = gid >> 3;                        // 64 elems per (b,l,h) row
    int b = row >> 15, rem = row & 32767;
    int l = rem >> 3, h = rem & 7;
    int lidx = ((b * H_ + h) << 12) + l;
    float l1 = Ls[lidx], l2 = Ls[B_ * H_ * L_ + lidx];
    float w1 = l1 / (l1 + l2), w2 = 1.f - w1;
    u16x8 a = *(const u16x8*)(On + off);
    u16x8 c = *(const u16x8*)(On + (size_t)M_ * F_ + off);
    u16 r[8];
#pragma unroll
    for (int j = 0; j < 8; ++j)
        r[j] = f2h(w1 * h2f(a[j]) + w2 * h2f(c[j]));
    *(u16x8*)(Ow + off) = *(u16x8*)r;
}

// ---------------------------------------------------------------------------
extern "C" void kernel_launch(void* const* d_in, const int* in_sizes, int n_in,
                              void* d_out, int out_size, void* d_ws, size_t ws_size,
                              hipStream_t stream)
{
    const float* Xq  = (const float*)d_in[0];
    const float* Xkv = (const float*)d_in[1];
    const float* Wq  = (const float*)d_in[2];
    const float* Wk  = (const float*)d_in[3];
    const float* Wv  = (const float*)d_in[4];
    const float* Wo  = (const float*)d_in[5];
    float* out = (float*)d_out;

    u16* ws  = (u16*)d_ws;
    const size_t MF = (size_t)M_ * F_;
    const size_t FF = (size_t)F_ * F_;
    u16* Wqt = ws;             // W^T 512x512 fp16 each
    u16* Wkt = Wqt + FF;
    u16* Wvt = Wkt + FF;
    u16* Wot = Wvt + FF;
    u16* Qw  = Wot + FF;       // [B,H,L,D] fp16, pre-scaled by log2e
    u16* Kw  = Qw + MF;        // [B,H,L,D] fp16
    u16* Vw  = Kw + MF;        // [B,H,D,L] bf16
    u16* On  = Vw + MF;        // 2 x [B,L,H*D] fp16 split partials
    float* Ls = (float*)(On + 2 * MF);  // 2 x [BH, L] f32
    u16* Ow  = Qw;             // reduced O aliases Qw (dead after flash)

    wt_kernel<<<dim3(16, 16, 4), 256, 0, stream>>>(Wq, Wk, Wv, Wo,
                                                   Wqt, Wkt, Wvt, Wot);

    proj_kernel<<<dim3(64, 8, 2), 256, 0, stream>>>(Xq, Xkv, Wqt, Wkt, Wvt,
                                                    Qw, Kw, Vw);

    flash_mfma<<<dim3(512), 256, 0, stream>>>(Qw, Kw, Vw, On, Ls);

    reduce_kernel<<<dim3((int)(MF / 8 / 256)), 256, 0, stream>>>(On, Ls, Ow);

    out_gemm<<<dim3(64, 4), 256, 0, stream>>>(Ow, Wot, out);
}

// Round 12
// 198.493 us; speedup vs baseline: 1.0171x; 1.0171x over previous
//
#include <hip/hip_runtime.h>
#include <hip/hip_bf16.h>

typedef short bf16x8 __attribute__((ext_vector_type(8)));
typedef _Float16 f16;
typedef f16 f16x8 __attribute__((ext_vector_type(8)));
typedef float f32x4 __attribute__((ext_vector_type(4)));
typedef unsigned short u16;
typedef u16 u16x8 __attribute__((ext_vector_type(8)));
typedef unsigned int u32;
typedef u32 u32x2 __attribute__((ext_vector_type(2)));

#define B_  2
#define L_  4096
#define F_  512
#define H_  8
#define D_  64
#define M_  8192       // B_*L_
#define NSPL 2         // flash split-K factor
#define KHALF (L_ / NSPL)

#define LOG2E 1.442695041f

__device__ inline u16 f2bf(float f) {
    union { float f; unsigned u; } v; v.f = f;
    unsigned r = v.u + 0x7fff + ((v.u >> 16) & 1);  // RNE
    return (u16)(r >> 16);
}
__device__ inline u16 f2h(float f) {
    union { f16 h; u16 u; } v; v.h = (f16)f;  // RNE hw cvt
    return v.u;
}
__device__ inline float h2f(u16 u) {
    union { u16 u; f16 h; } v; v.u = u;
    return (float)v.h;
}

// ---------------------------------------------------------------------------
// Fused weight transpose: W [512 k][512 n] fp32 -> Wt [512 n][512 k] fp16.
// ---------------------------------------------------------------------------
__global__ __launch_bounds__(256) void wt_kernel(
    const float* __restrict__ Wq, const float* __restrict__ Wk,
    const float* __restrict__ Wv, const float* __restrict__ Wo,
    u16* __restrict__ Tq, u16* __restrict__ Tk,
    u16* __restrict__ Tv, u16* __restrict__ To) {
    __shared__ float t[32][33];
    const int z = blockIdx.z;
    const float* in = (z == 0) ? Wq : (z == 1) ? Wk : (z == 2) ? Wv : Wo;
    u16* out = (z == 0) ? Tq : (z == 1) ? Tk : (z == 2) ? Tv : To;
    int k0 = blockIdx.y * 32, n0 = blockIdx.x * 32;
    int c = threadIdx.x & 31, r8 = threadIdx.x >> 5;
#pragma unroll
    for (int i = 0; i < 4; ++i) {
        int r = r8 * 4 + i;
        t[r][c] = in[(size_t)(k0 + r) * F_ + n0 + c];
    }
    __syncthreads();
#pragma unroll
    for (int i = 0; i < 4; ++i) {
        int r = r8 * 4 + i;
        out[(size_t)(n0 + r) * F_ + k0 + c] = f2h(t[c][r]);
    }
}

// ---------------------------------------------------------------------------
// Fused projection kernel (R9 form): 128x64 tile, m-major grid
// (XCD = m%8 owns a 2+2 MB A panel, L2-local; A read once for K+V).
// z=0: Q = Xq*Wq (scaled log2e) -> [B,H,L,D] fp16.
// z=1: K -> [B,H,L,D] fp16;  V -> [B,H,D,L] bf16 transposed.
// ---------------------------------------------------------------------------
__global__ __launch_bounds__(256, 3) void proj_kernel(
    const float* __restrict__ Xq, const float* __restrict__ Xkv,
    const u16* __restrict__ Wqt, const u16* __restrict__ Wkt,
    const u16* __restrict__ Wvt,
    u16* __restrict__ Qw, u16* __restrict__ Kw, u16* __restrict__ Vw) {
    __shared__ u16 Ah[128][72];
    __shared__ u16 B1[64][72];
    __shared__ u16 B2[64][72];
    const int tid = threadIdx.x;
    const int w = tid >> 6, lane = tid & 63, lx = lane & 15, quad = lane >> 4;
    const int m0 = blockIdx.x * 128, n0 = blockIdx.y * 64;
    const bool isKV = (blockIdx.z == 1);
    const float* A = isKV ? Xkv : Xq;
    const u16* W1 = isKV ? Wkt : Wqt;

    float4 apre[8];
    u16x8 b1p[2], b2p[2];

    auto load_ab = [&](int k0) {
#pragma unroll
        for (int it = 0; it < 4; ++it) {
            int slot = tid + it * 256, r = slot >> 3, g = (slot & 7) * 8;
            apre[2 * it]     = *(const float4*)(A + (size_t)(m0 + r) * F_ + k0 + g);
            apre[2 * it + 1] = *(const float4*)(A + (size_t)(m0 + r) * F_ + k0 + g + 4);
        }
#pragma unroll
        for (int it = 0; it < 2; ++it) {
            int slot = tid + it * 256, r = slot >> 3, g = (slot & 7) * 8;
            b1p[it] = *(const u16x8*)(W1 + (size_t)(n0 + r) * F_ + k0 + g);
            if (isKV)
                b2p[it] = *(const u16x8*)(Wvt + (size_t)(n0 + r) * F_ + k0 + g);
        }
    };
    auto write_ab = [&]() {
#pragma unroll
        for (int it = 0; it < 4; ++it) {
            int slot = tid + it * 256, r = slot >> 3, g = (slot & 7) * 8;
            float4 f0 = apre[2 * it], f1 = apre[2 * it + 1];
            u16 th[8] = {f2h(f0.x), f2h(f0.y), f2h(f0.z), f2h(f0.w),
                         f2h(f1.x), f2h(f1.y), f2h(f1.z), f2h(f1.w)};
            *(u16x8*)&Ah[r][g] = *(u16x8*)th;
        }
#pragma unroll
        for (int it = 0; it < 2; ++it) {
            int slot = tid + it * 256, r = slot >> 3, g = (slot & 7) * 8;
            *(u16x8*)&B1[r][g] = b1p[it];
            if (isKV) *(u16x8*)&B2[r][g] = b2p[it];
        }
    };

    f32x4 acc1[2][4] = {}, acc2[2][4] = {};

    load_ab(0);
    write_ab();
    __syncthreads();
    load_ab(64);   // in flight during first compute

    for (int k0 = 0; k0 < F_; k0 += 64) {
#pragma unroll
        for (int ks = 0; ks < 2; ++ks) {
            f16x8 af[2];
#pragma unroll
            for (int mf = 0; mf < 2; ++mf)
                af[mf] = *(const f16x8*)&Ah[w * 32 + mf * 16 + lx][ks * 32 + quad * 8];
#pragma unroll
            for (int nt = 0; nt < 4; ++nt) {
                f16x8 b1 = *(const f16x8*)&B1[nt * 16 + lx][ks * 32 + quad * 8];
#pragma unroll
                for (int mf = 0; mf < 2; ++mf)
                    acc1[mf][nt] = __builtin_amdgcn_mfma_f32_16x16x32_f16(af[mf], b1, acc1[mf][nt], 0, 0, 0);
                if (isKV) {
                    f16x8 b2 = *(const f16x8*)&B2[nt * 16 + lx][ks * 32 + quad * 8];
#pragma unroll
                    for (int mf = 0; mf < 2; ++mf)
                        acc2[mf][nt] = __builtin_amdgcn_mfma_f32_16x16x32_f16(af[mf], b2, acc2[mf][nt], 0, 0, 0);
                }
            }
        }
        if (k0 < F_ - 64) {
            __syncthreads();   // loads for k0+64 landed during this compute
            write_ab();
            __syncthreads();
            if (k0 < F_ - 128) load_ab(k0 + 128);  // issued AFTER barriers
        }
    }

    const int h = n0 >> 6;
    const float scl = isKV ? 1.0f : LOG2E;
    u16* C1 = isKV ? Kw : Qw;
#pragma unroll
    for (int mf = 0; mf < 2; ++mf)
#pragma unroll
        for (int nt = 0; nt < 4; ++nt)
#pragma unroll
            for (int i = 0; i < 4; ++i) {
                int m = m0 + w * 32 + mf * 16 + quad * 4 + i;
                int b = m >> 12, l = m & 4095;
                int d = nt * 16 + lx;
                C1[((size_t)(b * H_ + h) * L_ + l) * D_ + d] = f2h(acc1[mf][nt][i] * scl);
            }
    if (isKV) {
        __syncthreads();
#pragma unroll
        for (int mf = 0; mf < 2; ++mf)
#pragma unroll
            for (int nt = 0; nt < 4; ++nt)
#pragma unroll
                for (int i = 0; i < 4; ++i)
                    Ah[w * 32 + mf * 16 + quad * 4 + i][nt * 16 + lx] = f2bf(acc2[mf][nt][i]);
        __syncthreads();
        int d = tid >> 2, seg = (tid & 3) * 32;
        int b = m0 >> 12;
        u16 tmp[32];
#pragma unroll
        for (int j = 0; j < 32; ++j) tmp[j] = Ah[seg + j][d];
        size_t base = ((size_t)(b * H_ + h) * D_ + d) * L_ + (m0 & 4095) + seg;
#pragma unroll
        for (int c = 0; c < 4; ++c)
            *(u16x8*)(Vw + base + c * 8) = *(u16x8*)&tmp[c * 8];
    }
}

// ---------------------------------------------------------------------------
// Out-projection GEMM, 128x128 tile, m-major grid (XCD = m%8, L2-local).
// ---------------------------------------------------------------------------
__global__ __launch_bounds__(256) void out_gemm(const u16* __restrict__ A16,
                                                const u16* __restrict__ Wt,
                                                float* __restrict__ Cf) {
    __shared__ u16 As[128][72];
    __shared__ u16 Bs[128][72];
    const int tid = threadIdx.x;
    const int w = tid >> 6, lane = tid & 63, lx = lane & 15, quad = lane >> 4;
    const int m0 = blockIdx.x * 128, n0 = blockIdx.y * 128;

    u16x8 a16p[4];
    u16x8 bp[4];

    auto load_ab = [&](int k0) {
#pragma unroll
        for (int it = 0; it < 4; ++it) {
            int slot = tid + it * 256, r = slot >> 3, g = (slot & 7) * 8;
            a16p[it] = *(const u16x8*)(A16 + (size_t)(m0 + r) * F_ + k0 + g);
            bp[it]   = *(const u16x8*)(Wt  + (size_t)(n0 + r) * F_ + k0 + g);
        }
    };
    auto write_ab = [&]() {
#pragma unroll
        for (int it = 0; it < 4; ++it) {
            int slot = tid + it * 256, r = slot >> 3, g = (slot & 7) * 8;
            *(u16x8*)&As[r][g] = a16p[it];
            *(u16x8*)&Bs[r][g] = bp[it];
        }
    };

    f32x4 acc[2][8] = {};

    load_ab(0);
    write_ab();
    __syncthreads();
    load_ab(64);

    for (int k0 = 0; k0 < F_; k0 += 64) {
#pragma unroll
        for (int ks = 0; ks < 2; ++ks) {
            f16x8 af[2];
#pragma unroll
            for (int mf = 0; mf < 2; ++mf)
                af[mf] = *(const f16x8*)&As[w * 32 + mf * 16 + lx][ks * 32 + quad * 8];
#pragma unroll
            for (int nt = 0; nt < 8; ++nt) {
                f16x8 bf = *(const f16x8*)&Bs[nt * 16 + lx][ks * 32 + quad * 8];
#pragma unroll
                for (int mf = 0; mf < 2; ++mf)
                    acc[mf][nt] = __builtin_amdgcn_mfma_f32_16x16x32_f16(af[mf], bf, acc[mf][nt], 0, 0, 0);
            }
        }
        if (k0 < F_ - 64) {
            __syncthreads();
            write_ab();
            __syncthreads();
            if (k0 < F_ - 128) load_ab(k0 + 128);
        }
    }

#pragma unroll
    for (int mf = 0; mf < 2; ++mf)
#pragma unroll
        for (int nt = 0; nt < 8; ++nt)
#pragma unroll
            for (int i = 0; i < 4; ++i) {
                int m = m0 + w * 32 + mf * 16 + quad * 4 + i;
                int n = n0 + nt * 16 + lx;
                Cf[(size_t)m * F_ + n] = acc[mf][nt][i];
            }
}

// ---------------------------------------------------------------------------
// MFMA flash attention, R12 (final compose): R10 interleaved structure WITH
// setprio — the R11 A/B showed removing it costs +2.7 us (m191 mechanism:
// 2 waves/SIMD from different blocks at independent phases; priority lets
// the MFMA-phase wave preempt). 77.1 us measured = ~892 TF, at the
// plain-HIP 8-warp attention reference; beyond needs the full HK 4-cluster
// rewrite (T16), which does not decompose into safe incremental grafts.
// Structure: BQ=256 (4 waves x 64q), split-K x2, Q in regs, P in regs
// (permlane swap), K/V LDS dbuf, one barrier per kt, prefetch after the
// barrier, MFMA<->VALU interleave (softmax in the MFMA shadow).
// ---------------------------------------------------------------------------
__global__ __launch_bounds__(256, 2) void flash_mfma(
    const u16* __restrict__ Qg, const u16* __restrict__ Kg,
    const u16* __restrict__ Vtg, u16* __restrict__ On, float* __restrict__ Ls) {
    __shared__ u16 Ks[2][64][72];   // fp16, double-buffered
    __shared__ u16 Vs[2][64][72];   // bf16, V^T tile [d][kcol], double-buffered

    const int tid = threadIdx.x;
    const int w = tid >> 6, lane = tid & 63, lx = lane & 15, quad = lane >> 4;

    // decode: 512 = 8 xcd * (2 head * 2 split * 16 qtile)
    const int x = blockIdx.x;
    const int t = x >> 3;
    const int hh = t >> 5;
    const int s = (t >> 4) & 1;
    const int bh = (x & 7) * 2 + hh;
    const int q0 = (t & 15) * 256;

    const u16* Qp = Qg + ((size_t)bh * L_ + q0) * D_;
    const u16* Kp = Kg + (size_t)bh * L_ * D_ + (size_t)(s * KHALF) * D_;
    const u16* Vp = Vtg + (size_t)bh * D_ * L_ + s * KHALF;

    // Q fragments straight to registers (B-operand layout), 64 q-rows/wave
    f16x8 qreg[4][2];
#pragma unroll
    for (int qf = 0; qf < 4; ++qf)
#pragma unroll
        for (int ks = 0; ks < 2; ++ks)
            qreg[qf][ks] = *(const f16x8*)(Qp + (size_t)(w * 64 + qf * 16 + lx) * D_ +
                                           ks * 32 + quad * 8);

    u16x8 kp[2], vp[2];
    auto load_kv = [&](int kt) {
#pragma unroll
        for (int it = 0; it < 2; ++it) {
            int slot = tid + it * 256, r = slot >> 3, g = (slot & 7) * 8;
            kp[it] = *(const u16x8*)(Kp + (size_t)(kt * 64 + r) * D_ + g);
            vp[it] = *(const u16x8*)(Vp + (size_t)r * L_ + kt * 64 + g);
        }
    };
    auto write_kv = [&](int p) {
#pragma unroll
        for (int it = 0; it < 2; ++it) {
            int slot = tid + it * 256, r = slot >> 3, g = (slot & 7) * 8;
            *(u16x8*)&Ks[p][r][g] = kp[it];
            *(u16x8*)&Vs[p][r][g] = vp[it];
        }
    };

    // softmax of one half for one qf: sv pair -> bf16 A-fragment (permlane)
    auto smqf = [&](const f32x4& s0, const f32x4& s1) -> bf16x8 {
        u32 ub0[4], ub1[4];
#pragma unroll
        for (int i = 0; i < 4; ++i) {
            ub0[i] = __float_as_uint(__builtin_amdgcn_exp2f(s0[i]));
            ub1[i] = __float_as_uint(__builtin_amdgcn_exp2f(s1[i]));
        }
        u32 pu0 = __builtin_amdgcn_perm(ub0[1], ub0[0], 0x07060302u);
        u32 pw0 = __builtin_amdgcn_perm(ub0[3], ub0[2], 0x07060302u);
        u32 pu1 = __builtin_amdgcn_perm(ub1[1], ub1[0], 0x07060302u);
        u32 pw1 = __builtin_amdgcn_perm(ub1[3], ub1[2], 0x07060302u);
        u32x2 r  = __builtin_amdgcn_permlane32_swap(pu0, pu1, false, false);
        u32x2 r2 = __builtin_amdgcn_permlane16_swap(r[0], r[1], false, false);
        u32x2 tt = __builtin_amdgcn_permlane32_swap(pw0, pw1, false, false);
        u32x2 t2 = __builtin_amdgcn_permlane16_swap(tt[0], tt[1], false, false);
        union { u32 d[4]; bf16x8 h; } cvt;
        cvt.d[0] = r2[0];
        cvt.d[1] = t2[0];
        cvt.d[2] = r2[1];
        cvt.d[3] = t2[1];
        return cvt.h;
    };

    const bf16x8 vone = {0x3F80, 0x3F80, 0x3F80, 0x3F80,
                         0x3F80, 0x3F80, 0x3F80, 0x3F80};  // bf16 1.0 x8
    f32x4 o[4][4] = {};
    f32x4 osum[4] = {};

    load_kv(0);
    write_kv(0);
    __syncthreads();
    load_kv(1);   // in flight during first compute

    const int NT = KHALF / 64;
    for (int kt = 0; kt < NT; ++kt) {
        const int p = kt & 1;

        // ---- section 1: QK half A (nt 0,1), 16 MFMAs ---------------------
        // S^T = K Q^T : lane holds S^T[k=nt*16+quad*4+i][q=w*64+qf*16+lx]
        f32x4 sv[4][4] = {};
#pragma unroll
        for (int ks = 0; ks < 2; ++ks)
#pragma unroll
            for (int nt = 0; nt < 2; ++nt) {
                f16x8 ak = *(const f16x8*)&Ks[p][nt * 16 + lx][ks * 32 + quad * 8];
#pragma unroll
                for (int qf = 0; qf < 4; ++qf)
                    sv[nt][qf] = __builtin_amdgcn_mfma_f32_16x16x32_f16(ak, qreg[qf][ks], sv[nt][qf], 0, 0, 0);
            }

        // hoist half-B K fragments (4 ds_reads) for the interleave
        f16x8 akB[2][2];  // [ks][nt-2]
#pragma unroll
        for (int ks = 0; ks < 2; ++ks)
#pragma unroll
            for (int nt = 0; nt < 2; ++nt)
                akB[ks][nt] = *(const f16x8*)&Ks[p][(nt + 2) * 16 + lx][ks * 32 + quad * 8];

        // ---- section 2: per qf {4 QK_B MFMAs ; SM_A(qf) VALU} ------------
        bf16x8 apA[4];
#pragma unroll
        for (int qf = 0; qf < 4; ++qf) {
            sv[2][qf] = __builtin_amdgcn_mfma_f32_16x16x32_f16(akB[0][0], qreg[qf][0], sv[2][qf], 0, 0, 0);
            sv[3][qf] = __builtin_amdgcn_mfma_f32_16x16x32_f16(akB[0][1], qreg[qf][0], sv[3][qf], 0, 0, 0);
            sv[2][qf] = __builtin_amdgcn_mfma_f32_16x16x32_f16(akB[1][0], qreg[qf][1], sv[2][qf], 0, 0, 0);
            sv[3][qf] = __builtin_amdgcn_mfma_f32_16x16x32_f16(akB[1][1], qreg[qf][1], sv[3][qf], 0, 0, 0);
            apA[qf] = smqf(sv[0][qf], sv[1][qf]);   // VALU fills MFMA shadow
        }

        // stage next tile into the other buffer (regs loaded ≥1 kt ago)
        if (kt < NT - 1) write_kv(p ^ 1);

        // hoist V fragments for half A (ds_reads)
        bf16x8 bvA[4];
#pragma unroll
        for (int nt = 0; nt < 4; ++nt)
            bvA[nt] = *(const bf16x8*)&Vs[p][nt * 16 + lx][quad * 8];

        // ---- section 3: per qf {5 PV_A MFMAs ; SM_B(qf) VALU} ------------
        __builtin_amdgcn_s_setprio(1);
        bf16x8 apB[4];
#pragma unroll
        for (int qf = 0; qf < 4; ++qf) {
            osum[qf] = __builtin_amdgcn_mfma_f32_16x16x32_bf16(apA[qf], vone, osum[qf], 0, 0, 0);
#pragma unroll
            for (int nt = 0; nt < 4; ++nt)
                o[qf][nt] = __builtin_amdgcn_mfma_f32_16x16x32_bf16(apA[qf], bvA[nt], o[qf][nt], 0, 0, 0);
            apB[qf] = smqf(sv[2][qf], sv[3][qf]);   // VALU fills MFMA shadow
        }

        // ---- section 4: PV half B, 20 MFMAs ------------------------------
        bf16x8 bvB[4];
#pragma unroll
        for (int nt = 0; nt < 4; ++nt)
            bvB[nt] = *(const bf16x8*)&Vs[p][nt * 16 + lx][32 + quad * 8];
#pragma unroll
        for (int qf = 0; qf < 4; ++qf)
            osum[qf] = __builtin_amdgcn_mfma_f32_16x16x32_bf16(apB[qf], vone, osum[qf], 0, 0, 0);
#pragma unroll
        for (int nt = 0; nt < 4; ++nt) {
#pragma unroll
            for (int qf = 0; qf < 4; ++qf)
                o[qf][nt] = __builtin_amdgcn_mfma_f32_16x16x32_bf16(apB[qf], bvB[nt], o[qf][nt], 0, 0, 0);
        }
        __builtin_amdgcn_s_setprio(0);

        if (kt < NT - 1) __syncthreads();  // drains LDS writes + OLD loads only
        if (kt < NT - 2) load_kv(kt + 2);  // issued AFTER the barrier
    }

    // write On = O/l (fp16, [B,L,H*D]) and l (f32)
    const int b = bh >> 3, h = bh & 7;
    u16* Op = On + (size_t)s * M_ * F_;
#pragma unroll
    for (int qf = 0; qf < 4; ++qf) {
        float linv[4];
#pragma unroll
        for (int i = 0; i < 4; ++i) linv[i] = 1.f / osum[qf][i];
#pragma unroll
        for (int nt = 0; nt < 4; ++nt)
#pragma unroll
            for (int i = 0; i < 4; ++i) {
                int l = q0 + w * 64 + qf * 16 + quad * 4 + i;
                Op[((size_t)b * L_ + l) * (H_ * D_) + h * D_ + nt * 16 + lx] =
                    f2h(o[qf][nt][i] * linv[i]);
            }
        if (lx == 0) {
            float* lp = Ls + ((size_t)s * (B_ * H_) + bh) * L_ +
                        q0 + w * 64 + qf * 16 + quad * 4;
#pragma unroll
            for (int i = 0; i < 4; ++i) lp[i] = osum[qf][i];
        }
    }
}

// ---------------------------------------------------------------------------
// Combine split-K partials: O = (l1*O1n + l2*O2n) / (l1+l2).
// ---------------------------------------------------------------------------
__global__ __launch_bounds__(256) void reduce_kernel(
    const u16* __restrict__ On, const float* __restrict__ Ls,
    u16* __restrict__ Ow) {
    int gid = blockIdx.x * 256 + threadIdx.x;  // u16x8 group, grid covers M_*F_/8
    size_t off = (size_t)gid * 8;
    int row = gid >> 3;                        // 64 elems per (b,l,h) row
    int b = row >> 15, rem = row & 32767;
    int l = rem >> 3, h = rem & 7;
    int lidx = ((b * H_ + h) << 12) + l;
    float l1 = Ls[lidx], l2 = Ls[B_ * H_ * L_ + lidx];
    float w1 = l1 / (l1 + l2), w2 = 1.f - w1;
    u16x8 a = *(const u16x8*)(On + off);
    u16x8 c = *(const u16x8*)(On + (size_t)M_ * F_ + off);
    u16 r[8];
#pragma unroll
    for (int j = 0; j < 8; ++j)
        r[j] = f2h(w1 * h2f(a[j]) + w2 * h2f(c[j]));
    *(u16x8*)(Ow + off) = *(u16x8*)r;
}

// ---------------------------------------------------------------------------
extern "C" void kernel_launch(void* const* d_in, const int* in_sizes, int n_in,
                              void* d_out, int out_size, void* d_ws, size_t ws_size,
                              hipStream_t stream)
{
    const float* Xq  = (const float*)d_in[0];
    const float* Xkv = (const float*)d_in[1];
    const float* Wq  = (const float*)d_in[2];
    const float* Wk  = (const float*)d_in[3];
    const float* Wv  = (const float*)d_in[4];
    const float* Wo  = (const float*)d_in[5];
    float* out = (float*)d_out;

    u16* ws  = (u16*)d_ws;
    const size_t MF = (size_t)M_ * F_;
    const size_t FF = (size_t)F_ * F_;
    u16* Wqt = ws;             // W^T 512x512 fp16 each
    u16* Wkt = Wqt + FF;
    u16* Wvt = Wkt + FF;
    u16* Wot = Wvt + FF;
    u16* Qw  = Wot + FF;       // [B,H,L,D] fp16, pre-scaled by log2e
    u16* Kw  = Qw + MF;        // [B,H,L,D] fp16
    u16* Vw  = Kw + MF;        // [B,H,D,L] bf16
    u16* On  = Vw + MF;        // 2 x [B,L,H*D] fp16 split partials
    float* Ls = (float*)(On + 2 * MF);  // 2 x [BH, L] f32
    u16* Ow  = Qw;             // reduced O aliases Qw (dead after flash)

    wt_kernel<<<dim3(16, 16, 4), 256, 0, stream>>>(Wq, Wk, Wv, Wo,
                                                   Wqt, Wkt, Wvt, Wot);

    proj_kernel<<<dim3(64, 8, 2), 256, 0, stream>>>(Xq, Xkv, Wqt, Wkt, Wvt,
                                                    Qw, Kw, Vw);

    flash_mfma<<<dim3(512), 256, 0, stream>>>(Qw, Kw, Vw, On, Ls);

    reduce_kernel<<<dim3((int)(MF / 8 / 256)), 256, 0, stream>>>(On, Ls, Ow);

    out_gemm<<<dim3(64, 4), 256, 0, stream>>>(Ow, Wot, out);
}